// Round 7
// baseline (345.597 us; speedup 1.0000x reference)
//
#include <hip/hip_runtime.h>
#include <stdint.h>
#include <stddef.h>

#define NN 100000
#define NE 1600000
#define DD 32
#define NCAND 1024
#define HSIZE 65536
#define SORTN 4096
#define NBUK ((NN + 255) / 256)            // 391 buckets of 256 rows
#define EPB 4096                           // edges per block in kA2
#define BCAP 5120                          // padded bucket capacity (global pkBin)
#define BCAPL 4608                         // LDS working capacity (mean 4096 + 8 sd)
#define CHK 5                              // per-thread chunk in kB_emit (1024 thr)

// capacity for per-stage packed lists (mean + huge margin)
#define CAP1 832000
#define CAP2 432000
#define CAP3 240000

// ---------------- JAX threefry2x32 (20 rounds) ----------------
__host__ __device__ inline void tf2x32(uint32_t k0, uint32_t k1, uint32_t x0, uint32_t x1,
                                       uint32_t& o0, uint32_t& o1) {
  uint32_t ks2 = k0 ^ k1 ^ 0x1BD11BDAu;
  uint32_t v0 = x0 + k0, v1 = x1 + k1;
#define TFR(r) { v0 += v1; v1 = (v1 << (r)) | (v1 >> (32 - (r))); v1 ^= v0; }
  TFR(13) TFR(15) TFR(26) TFR(6)   v0 += k1;  v1 += ks2 + 1u;
  TFR(17) TFR(29) TFR(16) TFR(24)  v0 += ks2; v1 += k0 + 2u;
  TFR(13) TFR(15) TFR(26) TFR(6)   v0 += k0;  v1 += k1 + 3u;
  TFR(17) TFR(29) TFR(16) TFR(24)  v0 += k1;  v1 += ks2 + 4u;
  TFR(13) TFR(15) TFR(26) TFR(6)   v0 += ks2; v1 += k0 + 5u;
#undef TFR
  o0 = v0; o1 = v1;
}

__device__ __forceinline__ uint32_t jax_bits32(uint32_t k0, uint32_t k1, uint32_t i) {
  uint32_t o0, o1;
  tf2x32(k0, k1, 0u, i, o0, o1);
  return o0 ^ o1;
}

__device__ __forceinline__ float bits_to_uniform(uint32_t b) {
  return __fsub_rn(__uint_as_float((b >> 9) | 0x3f800000u), 1.0f);
}

// ---- numpy-pairwise sum of 32 floats held as 8 float4 REGISTERS ----
// Exact replication of the original pairwise32 association (no local
// arrays -> no scratch spill).
__device__ __forceinline__ float pw32c(float4 c0, float4 c1, float4 c2, float4 c3,
                                       float4 c4, float4 c5, float4 c6, float4 c7) {
  float r0 = __fadd_rn(__fadd_rn(__fadd_rn(c0.x, c2.x), c4.x), c6.x);
  float r1 = __fadd_rn(__fadd_rn(__fadd_rn(c0.y, c2.y), c4.y), c6.y);
  float r2 = __fadd_rn(__fadd_rn(__fadd_rn(c0.z, c2.z), c4.z), c6.z);
  float r3 = __fadd_rn(__fadd_rn(__fadd_rn(c0.w, c2.w), c4.w), c6.w);
  float r4 = __fadd_rn(__fadd_rn(__fadd_rn(c1.x, c3.x), c5.x), c7.x);
  float r5 = __fadd_rn(__fadd_rn(__fadd_rn(c1.y, c3.y), c5.y), c7.y);
  float r6 = __fadd_rn(__fadd_rn(__fadd_rn(c1.z, c3.z), c5.z), c7.z);
  float r7 = __fadd_rn(__fadd_rn(__fadd_rn(c1.w, c3.w), c5.w), c7.w);
  float a01 = __fadd_rn(r0, r1), a23 = __fadd_rn(r2, r3);
  float a45 = __fadd_rn(r4, r5), a67 = __fadd_rn(r6, r7);
  return __fadd_rn(__fadd_rn(a01, a23), __fadd_rn(a45, a67));
}

__device__ __forceinline__ float4 f4div1(float4 a, float d) {
  return make_float4(__fdiv_rn(a.x, d), __fdiv_rn(a.y, d),
                     __fdiv_rn(a.z, d), __fdiv_rn(a.w, d));
}
__device__ __forceinline__ float4 f4sq(float4 a) {
  return make_float4(__fmul_rn(a.x, a.x), __fmul_rn(a.y, a.y),
                     __fmul_rn(a.z, a.z), __fmul_rn(a.w, a.w));
}
__device__ __forceinline__ float4 f4dd(float4 s, float n1, float4 e, float n2) {
  return make_float4(__fmul_rn(__fdiv_rn(s.x, n1), __fdiv_rn(e.x, n2)),
                     __fmul_rn(__fdiv_rn(s.y, n1), __fdiv_rn(e.y, n2)),
                     __fmul_rn(__fdiv_rn(s.z, n1), __fdiv_rn(e.z, n2)),
                     __fmul_rn(__fdiv_rn(s.w, n1), __fdiv_rn(e.w, n2)));
}

// ---------------- preprocessing ----------------
// 1024-thread blocks at the same 391-block grid: the old 512-thread shape
// capped occupancy at 1.53 blk/CU x 8 waves = 12 waves/CU (38%); wider
// blocks double the resident-wave ceiling without deepening the global
// atomic chains (which rounds 3/5 showed must stay at 391).
__global__ __launch_bounds__(1024) void kA2_bin(
    const int* __restrict__ rows, const int* __restrict__ cols,
    const float* __restrict__ adj,
    uint32_t k00, uint32_t k01, uint32_t k10, uint32_t k11,
    uint32_t k20, uint32_t k21,
    int* __restrict__ bucketCursor, int4* __restrict__ pkBin,
    int* __restrict__ bucketCntS) {
  __shared__ int hist[NBUK];
  __shared__ int base[NBUK];
  __shared__ int h1[NBUK];
  __shared__ int h2[NBUK];
  __shared__ int h3[NBUK];
  __shared__ uint8_t lvs[EPB];
  __shared__ uint16_t rank16[EPB];
  int tid = threadIdx.x;
  for (int i = tid; i < NBUK; i += 1024) { hist[i] = 0; h1[i] = 0; h2[i] = 0; h3[i] = 0; }
  __syncthreads();
  int e0 = blockIdx.x * EPB;
#pragma unroll
  for (int k = 0; k < 4; ++k) {
    int e = e0 + k * 1024 + tid;
    int lv = 0;
    if (e < NE) {
      float u0 = bits_to_uniform(jax_bits32(k00, k01, (uint32_t)e));
      float u1 = bits_to_uniform(jax_bits32(k10, k11, (uint32_t)e));
      float u2 = bits_to_uniform(jax_bits32(k20, k21, (uint32_t)e));
      float kp0 = floorf(__fadd_rn(u0, 0.5f));
      float kp1 = floorf(__fadd_rn(u1, 0.25f));
      float kp2 = floorf(__fadd_rn(u2, 0.125f));
      if (kp0 != 0.0f) { lv = 1; if (kp1 != 0.0f) { lv = 2; if (kp2 != 0.0f) lv = 3; } }
      int b = rows[e] >> 8;
      rank16[k * 1024 + tid] = (uint16_t)atomicAdd(&hist[b], 1);
      if (lv >= 1) {
        atomicAdd(&h1[b], 1);
        if (lv >= 2) {
          atomicAdd(&h2[b], 1);
          if (lv >= 3) atomicAdd(&h3[b], 1);
        }
      }
    }
    lvs[k * 1024 + tid] = (uint8_t)lv;
  }
  __syncthreads();
  // bucketCursor's final value IS the level-0 total; no separate cnt0 atomic.
  for (int i = tid; i < NBUK; i += 1024) {
    int h = hist[i];
    base[i] = (h > 0) ? atomicAdd(&bucketCursor[i], h) : 0;
    if (h1[i]) atomicAdd(&bucketCntS[i], h1[i]);
    if (h2[i]) atomicAdd(&bucketCntS[NBUK + i], h2[i]);
    if (h3[i]) atomicAdd(&bucketCntS[2 * NBUK + i], h3[i]);
  }
  __syncthreads();
#pragma unroll
  for (int k = 0; k < 4; ++k) {
    int e = e0 + k * 1024 + tid;
    if (e < NE) {
      int r = rows[e];
      int b = r >> 8;
      int lv = (int)lvs[k * 1024 + tid];
      int pos = base[b] + (int)rank16[k * 1024 + tid];
      if (pos < BCAP)  // overflow guard (P~0)
        pkBin[(size_t)b * BCAP + pos] =
            make_int4(cols[e], __float_as_int(adj[e]), (e << 2) | lv, r);
    }
  }
}

// block a: a==0 scans bucketCursor (level-0 totals); a=1..3 scan h-arrays.
__global__ __launch_bounds__(512) void k_scanBS(const int* __restrict__ bucketCursor,
                                                const int* __restrict__ bucketCntS,
                                                int* __restrict__ bucketBaseS) {
  __shared__ int sb[512];
  int a = blockIdx.x;
  const int* c = (a == 0) ? bucketCursor : (bucketCntS + (size_t)(a - 1) * NBUK);
  int* o = bucketBaseS + (size_t)a * (NBUK + 1);
  int tid = threadIdx.x;
  int v = (tid < NBUK) ? c[tid] : 0;
  sb[tid] = v;
  __syncthreads();
  for (int off = 1; off < 512; off <<= 1) {
    int x = (tid >= off) ? sb[tid - off] : 0;
    __syncthreads();
    sb[tid] += x;
    __syncthreads();
  }
  if (tid < NBUK) o[tid] = sb[tid] - v;
  if (tid == NBUK - 1) o[NBUK] = sb[tid];
}

// per-bucket (1024 threads): load keys once, group, parallel rank-by-counting
// sort, order sums, coalesced emit. LDS ~57 KB -> 2 blocks/CU by both LDS
// and thread limits; per-thread rank-scan chunk halves vs the 512 shape.
__global__ __launch_bounds__(1024) void kB_emit(
    const int* __restrict__ bucketBaseS, const int4* __restrict__ pkBin,
    int* __restrict__ rpAll,
    int2* __restrict__ pk0, int2* __restrict__ pk1,
    int2* __restrict__ pk2, int2* __restrict__ pk3,
    float* __restrict__ order0, float* __restrict__ order1, float* __restrict__ order2) {
  __shared__ unsigned long long cnt64[256];
  __shared__ unsigned long long scan64[1024];  // 256-scan (phase 2) then emit scan
  __shared__ int start0[256];
  __shared__ int cur[256];
  __shared__ uint32_t keyF[BCAPL];   // original-index keys; reused as adjS after sort
  __shared__ uint32_t keyG[BCAPL];   // grouped keys, permuted to sorted in place
  __shared__ uint16_t origG[BCAPL];  // grouped slot -> original index (sorted in place)
  int b = blockIdx.x, tid = threadIdx.x;
  int bB0 = bucketBaseS[b];
  int n = bucketBaseS[b + 1] - bB0;
  if (n > BCAPL) n = BCAPL;  // LDS-safety clamp (P~0)
  size_t sRead = (size_t)b * BCAP;
  const int* pkI = (const int*)pkBin;          // int view: [col, adj, eidlv, row]
  const int2* pkZW = (const int2*)pkBin;       // int2 view: idx 2*i+1 = (eidlv, row)
  int r0 = b << 8;
  int nr = NN - r0; if (nr > 256) nr = 256;
  int bB1 = bucketBaseS[(NBUK + 1) + b];
  int bB2 = bucketBaseS[2 * (NBUK + 1) + b];
  int bB3 = bucketBaseS[3 * (NBUK + 1) + b];
  if (tid < 256) { cnt64[tid] = 0ull; cur[tid] = 0; }
  __syncthreads();
  // phase 1: load key halves, stash keyF, count per-row per-level
  for (int i = tid; i < n; i += 1024) {
    int2 zw = pkZW[2 * (sRead + (size_t)i) + 1];  // (eidlv, row)
    int lr = zw.y - r0;
    int lv = zw.x & 3;
    keyF[i] = ((uint32_t)lr << 23) | (uint32_t)zw.x;
    unsigned long long add = 1ull;
    if (lv >= 1) add |= 1ull << 16;
    if (lv >= 2) add |= 1ull << 32;
    if (lv >= 3) add |= 1ull << 48;
    atomicAdd(&cnt64[lr], add);
  }
  __syncthreads();
  // phase 2: 256-wide exclusive scan of packed counts
  unsigned long long own = (tid < 256) ? cnt64[tid] : 0ull;
  if (tid < 256) scan64[tid] = own;
  __syncthreads();
  for (int off = 1; off < 256; off <<= 1) {
    unsigned long long v = (tid < 256 && tid >= off) ? scan64[tid - off] : 0ull;
    __syncthreads();
    if (tid < 256) scan64[tid] += v;
    __syncthreads();
  }
  if (tid < 256) {
    unsigned long long ex = scan64[tid] - own;
    start0[tid] = (int)(ex & 0xFFFFull);
    if (tid < nr) {
      rpAll[r0 + tid] = bB0 + (int)(ex & 0xFFFFull);
      rpAll[(NN + 1) + r0 + tid] = bB1 + (int)((ex >> 16) & 0xFFFFull);
      rpAll[2 * (NN + 1) + r0 + tid] = bB2 + (int)((ex >> 32) & 0xFFFFull);
      rpAll[3 * (NN + 1) + r0 + tid] = bB3 + (int)((ex >> 48) & 0xFFFFull);
    }
  }
  if (b == NBUK - 1 && tid == 0) {
    rpAll[NN] = bucketBaseS[NBUK];
    rpAll[(NN + 1) + NN] = bucketBaseS[(NBUK + 1) + NBUK];
    rpAll[2 * (NN + 1) + NN] = bucketBaseS[2 * (NBUK + 1) + NBUK];
    rpAll[3 * (NN + 1) + NN] = bucketBaseS[3 * (NBUK + 1) + NBUK];
  }
  __syncthreads();
  // phase 3: group (LDS->LDS), scattering both index and key
  for (int i = tid; i < n; i += 1024) {
    uint32_t k = keyF[i];
    int lr = (int)(k >> 23);
    int slot = start0[lr] + atomicAdd(&cur[lr], 1);
    origG[slot] = (uint16_t)i;
    keyG[slot] = k;
  }
  __syncthreads();
  // phase 4: parallel rank-by-counting sort of each row segment (keys
  // unique -> ranks are a permutation). Static register indexing.
  int C2 = (n + 1023) >> 10;  // <= CHK
  {
    int lo2 = tid * C2, hi2 = lo2 + C2;
    if (lo2 > n) lo2 = n;
    if (hi2 > n) hi2 = n;
    uint16_t vals[CHK];
    uint16_t pos[CHK];
    uint32_t keys[CHK];
#pragma unroll
    for (int q = 0; q < CHK; ++q) {
      int i = lo2 + q;
      if (i < hi2) {
        uint32_t ki = keyG[i];
        int lr = (int)(ki >> 23);
        int st = start0[lr];
        int d = (int)(cnt64[lr] & 0xFFFFull);
        int rank = 0;
        for (int j = 0; j < d; ++j) rank += (keyG[st + j] < ki) ? 1 : 0;
        vals[q] = origG[i];
        keys[q] = ki;
        pos[q] = (uint16_t)(st + rank);
      }
    }
    __syncthreads();
#pragma unroll
    for (int q = 0; q < CHK; ++q) {
      int i = lo2 + q;
      if (i < hi2) { origG[pos[q]] = vals[q]; keyG[pos[q]] = keys[q]; }
    }
  }
  __syncthreads();
  // phase 5: stage adj bits (sorted order) into dead keyF; register-batched
  // independent global loads (L2-resident bucket), static indexing.
  uint32_t* adjS = keyF;
  {
    uint32_t av[CHK];
#pragma unroll
    for (int q = 0; q < CHK; ++q) {
      int i = tid + q * 1024;
      if (i < n) av[q] = (uint32_t)pkI[4 * (sRead + (size_t)origG[i]) + 1];
    }
#pragma unroll
    for (int q = 0; q < CHK; ++q) {
      int i = tid + q * 1024;
      if (i < n) adjS[i] = av[q];
    }
  }
  __syncthreads();
  // phase 6: orders in sorted (reference) order — sequential LDS reads
  if (tid < nr) {
    int d = (int)(cnt64[tid] & 0xFFFFull);
    int st = start0[tid];
    float o0 = 0.0f, o1v = 0.0f, o2v = 0.0f;
    for (int i = 0; i < d; ++i) {
      int lv = (int)(keyG[st + i] & 3u);
      float a = __uint_as_float(adjS[st + i]);
      o0 = __fadd_rn(o0, a);
      if (lv >= 1) { o1v = __fadd_rn(o1v, a); if (lv >= 2) o2v = __fadd_rn(o2v, a); }
    }
    order0[r0 + tid] = o0; order1[r0 + tid] = o1v; order2[r0 + tid] = o2v;
  }
  // phase 7: chunked block scan of stage flags + coalesced emit
  int lo = tid * C2, hi = lo + C2;
  if (lo > n) lo = n;
  if (hi > n) hi = n;
  int c1 = 0, c2 = 0, c3 = 0;
  for (int i = lo; i < hi; ++i) {
    int lv = (int)(keyG[i] & 3u);
    c1 += (lv >= 1); c2 += (lv >= 2); c3 += (lv >= 3);
  }
  unsigned long long mine = (unsigned long long)c1 |
                            ((unsigned long long)c2 << 16) |
                            ((unsigned long long)c3 << 32);
  scan64[tid] = mine;
  __syncthreads();
  for (int off = 1; off < 1024; off <<= 1) {
    unsigned long long v = (tid >= off) ? scan64[tid - off] : 0ull;
    __syncthreads();
    scan64[tid] += v;
    __syncthreads();
  }
  unsigned long long ex = scan64[tid] - mine;
  int o1 = bB1 + (int)(ex & 0xFFFFull);
  int o2 = bB2 + (int)((ex >> 16) & 0xFFFFull);
  int o3 = bB3 + (int)((ex >> 32) & 0xFFFFull);
  {
    int colr[CHK];
#pragma unroll
    for (int q = 0; q < CHK; ++q) {
      int i = lo + q;
      if (i < hi) colr[q] = pkI[4 * (sRead + (size_t)origG[i])];
    }
#pragma unroll
    for (int q = 0; q < CHK; ++q) {
      int i = lo + q;
      if (i < hi) {
        int lv = (int)(keyG[i] & 3u);
        int2 pkv = make_int2(colr[q], (int)adjS[i]);
        pk0[bB0 + i] = pkv;  // sequential within bucket
        if (lv >= 1) {
          pk1[o1++] = pkv;
          if (lv >= 2) {
            pk2[o2++] = pkv;
            if (lv >= 3) pk3[o3++] = pkv;
          }
        }
      }
    }
  }
}

// ---------------- SpMM chain: 8-deep software-pipelined gathers ----------------

// fst_emb = spmm(adj, embeds) - embeds
__global__ void k_emb0(const int* __restrict__ rp, const int2* __restrict__ pk,
                       const float* __restrict__ embeds, float* __restrict__ e0) {
  int tid = blockIdx.x * blockDim.x + threadIdx.x;
  int r = tid >> 5, d = tid & 31;
  if (r >= NN) return;
  int s = rp[r], t = rp[r + 1];
  float acc = 0.0f;
  for (int base = s; base < t; base += 32) {
    int idx = base + d;
    int2 p = (idx < t) ? pk[idx] : make_int2(0, 0);
    int m = t - base; if (m > 32) m = 32;
    for (int j = 0; j < m; j += 8) {
      int cc[8], aa[8];
      float xx[8];
#pragma unroll
      for (int q = 0; q < 8; ++q) {
        cc[q] = __shfl(p.x, j + q, 32);
        aa[q] = __shfl(p.y, j + q, 32);
      }
#pragma unroll
      for (int q = 0; q < 8; ++q) xx[q] = embeds[(size_t)cc[q] * DD + d];
#pragma unroll
      for (int q = 0; q < 8; ++q)
        acc = __fadd_rn(acc, __fmul_rn(__int_as_float(aa[q]), xx[q]));
    }
  }
  e0[(size_t)r * DD + d] = __fsub_rn(acc, embeds[(size_t)r * DD + d]);
}

// FUSED emb+num step (lane d==0 writes num outputs)
// mode: 1 = sums init, write next; 2 = sums +=, write next; 3 = sums += only
__global__ void k_emb_step(const int* __restrict__ rp, const int2* __restrict__ pk,
                           const float* __restrict__ ord, const float* __restrict__ ecur,
                           float* __restrict__ enext, float* __restrict__ esum,
                           const float* __restrict__ ncur, float* __restrict__ nnext,
                           float* __restrict__ nsum, int mode) {
  int tid = blockIdx.x * blockDim.x + threadIdx.x;
  int r = tid >> 5, d = tid & 31;
  if (r >= NN) return;
  int s = rp[r], t = rp[r + 1];
  float acc = 0.0f, accn = 0.0f;
  for (int base = s; base < t; base += 32) {
    int idx = base + d;
    int2 p = (idx < t) ? pk[idx] : make_int2(0, 0);
    int m = t - base; if (m > 32) m = 32;
    for (int j = 0; j < m; j += 8) {
      int cc[8], aa[8];
      float xx[8], nn[8];
#pragma unroll
      for (int q = 0; q < 8; ++q) {
        cc[q] = __shfl(p.x, j + q, 32);
        aa[q] = __shfl(p.y, j + q, 32);
      }
#pragma unroll
      for (int q = 0; q < 8; ++q) {
        xx[q] = ecur[(size_t)cc[q] * DD + d];
        nn[q] = ncur[cc[q]];
      }
#pragma unroll
      for (int q = 0; q < 8; ++q) {
        float av = __int_as_float(aa[q]);
        acc = __fadd_rn(acc, __fmul_rn(av, xx[q]));
        accn = __fadd_rn(accn, __fmul_rn(av, nn[q]));
      }
    }
  }
  float ordv = ord[r];
  size_t idx = (size_t)r * DD + d;
  float ec = ecur[idx];
  float o = __fsub_rn(__fsub_rn(acc, ec), __fmul_rn(ordv, ec));
  if (mode != 3) enext[idx] = o;
  if (mode == 1) esum[idx] = __fadd_rn(ec, o);
  else esum[idx] = __fadd_rn(esum[idx], o);
  if (d == 0) {
    float nc = ncur[r];
    float on = __fsub_rn(__fsub_rn(accn, nc), ordv);
    if (mode != 3) nnext[r] = on;
    if (mode == 1) nsum[r] = __fadd_rn(nc, on);
    else nsum[r] = __fadd_rn(nsum[r], on);
  }
}

// Scores + histogram. All math on named float4 registers (no local
// arrays -> no scratch). Per-block LDS hash bounds global atomic chains.
__global__ __launch_bounds__(256) void k_final(
    const float* __restrict__ embeds, const float* __restrict__ emb_sum,
    const float* __restrict__ num_sum, uint32_t gk0, uint32_t gk1,
    float* __restrict__ out_scores, int* __restrict__ hist) {
  __shared__ uint32_t hb[512];
  __shared__ uint32_t hc[512];
  int r = blockIdx.x * blockDim.x + threadIdx.x;
  for (int i = threadIdx.x; i < 512; i += 256) { hb[i] = 0xFFFFFFFFu; hc[i] = 0u; }
  __syncthreads();
  if (r < NN) {
    float denom = __fadd_rn(num_sum[r], 1e-8f);
    const float4* ps = (const float4*)(emb_sum + (size_t)r * DD);
    const float4* pe = (const float4*)(embeds + (size_t)r * DD);
    float4 m0 = pe[0], m1 = pe[1], m2 = pe[2], m3 = pe[3],
           m4 = pe[4], m5 = pe[5], m6 = pe[6], m7 = pe[7];
    float4 s0 = f4div1(ps[0], denom), s1 = f4div1(ps[1], denom),
           s2 = f4div1(ps[2], denom), s3 = f4div1(ps[3], denom),
           s4 = f4div1(ps[4], denom), s5 = f4div1(ps[5], denom),
           s6 = f4div1(ps[6], denom), s7 = f4div1(ps[7], denom);
    float n1 = fmaxf(__fsqrt_rn(pw32c(f4sq(s0), f4sq(s1), f4sq(s2), f4sq(s3),
                                      f4sq(s4), f4sq(s5), f4sq(s6), f4sq(s7))), 1e-12f);
    float n2 = fmaxf(__fsqrt_rn(pw32c(f4sq(m0), f4sq(m1), f4sq(m2), f4sq(m3),
                                      f4sq(m4), f4sq(m5), f4sq(m6), f4sq(m7))), 1e-12f);
    float dot = pw32c(f4dd(s0, n1, m0, n2), f4dd(s1, n1, m1, n2),
                      f4dd(s2, n1, m2, n2), f4dd(s3, n1, m3, n2),
                      f4dd(s4, n1, m4, n2), f4dd(s5, n1, m5, n2),
                      f4dd(s6, n1, m6, n2), f4dd(s7, n1, m7, n2));
    float u = bits_to_uniform(jax_bits32(gk0, gk1, (uint32_t)r));
    float l1 = (float)log((double)u);
    float w = -l1;
    float l2 = (float)log((double)w);
    float g = -l2;
    float score = __fadd_rn(dot, g);
    out_scores[r] = score;
    uint32_t kb = __float_as_uint(score);
    kb = (kb & 0x80000000u) ? ~kb : (kb | 0x80000000u);
    uint32_t key = kb >> 16;
    uint32_t slot = (key * 2654435761u) >> 23;  // Fibonacci hash -> 9 bits
    for (;;) {
      uint32_t prev = atomicCAS(&hb[slot], 0xFFFFFFFFu, key);
      if (prev == 0xFFFFFFFFu || prev == key) { atomicAdd(&hc[slot], 1u); break; }
      slot = (slot + 1) & 511u;
    }
  }
  __syncthreads();
  for (int i = threadIdx.x; i < 512; i += 256)
    if (hb[i] != 0xFFFFFFFFu) atomicAdd(&hist[hb[i]], (int)hc[i]);
}

__global__ void k_cutoff(const int* __restrict__ hist, int* __restrict__ cutoff) {
  __shared__ int psum[1024];
  int t = threadIdx.x;
  int base = HSIZE - (t + 1) * 64;
  int own = 0;
  for (int i = 0; i < 64; ++i) own += hist[base + i];
  psum[t] = own;
  __syncthreads();
  for (int off = 1; off < 1024; off <<= 1) {
    int v = (t >= off) ? psum[t - off] : 0;
    __syncthreads();
    psum[t] += v;
    __syncthreads();
  }
  int incl = psum[t];
  int prev = incl - own;
  if (incl >= NCAND && prev < NCAND) {
    int c = prev;
    int b = HSIZE - t * 64 - 1;
    while (b >= base) {
      c += hist[b];
      if (c >= NCAND) break;
      --b;
    }
    *cutoff = b;
  }
}

__global__ void k_collect(const float* __restrict__ scores, const int* __restrict__ cutoff,
                          unsigned long long* __restrict__ buf, int* __restrict__ cnt2) {
  int r = blockIdx.x * blockDim.x + threadIdx.x;
  if (r >= NN) return;
  uint32_t kb = __float_as_uint(scores[r]);
  kb = (kb & 0x80000000u) ? ~kb : (kb | 0x80000000u);
  if ((int)(kb >> 16) >= *cutoff) {
    int p = atomicAdd(cnt2, 1);
    if (p < SORTN)
      buf[p] = ((unsigned long long)kb << 32) | (uint32_t)(~(uint32_t)r);
  }
}

// Rank-by-counting sort (keys unique -> ranks are a permutation; top NCAND
// ranks == descending-sorted top NCAND). 16 blocks, LDS broadcast reads.
__global__ __launch_bounds__(256) void k_rank(const unsigned long long* __restrict__ buf,
                                              const int* __restrict__ cnt2,
                                              float* __restrict__ out_cand) {
  __shared__ unsigned long long s[SORTN];
  int m = *cnt2;
  if (m > SORTN) m = SORTN;
  if (blockIdx.x * 256 >= m) return;  // whole block idle -> skip load
  for (int i = threadIdx.x; i < m; i += 256) s[i] = buf[i];
  __syncthreads();
  int i = blockIdx.x * 256 + threadIdx.x;
  if (i >= m) return;
  unsigned long long mine = s[i];
  int rank = 0;
  int j = 0;
  for (; j + 8 <= m; j += 8) {
#pragma unroll
    for (int q = 0; q < 8; ++q) rank += (s[j + q] > mine) ? 1 : 0;
  }
  for (; j < m; ++j) rank += (s[j] > mine) ? 1 : 0;
  if (rank < NCAND) {
    uint32_t idx = ~((uint32_t)(mine & 0xffffffffull));
    out_cand[rank] = (float)idx;
  }
}

// ---------------- host ----------------
extern "C" void kernel_launch(void* const* d_in, const int* in_sizes, int n_in,
                              void* d_out, int out_size, void* d_ws, size_t ws_size,
                              hipStream_t stream) {
  const int* rows = (const int*)d_in[0];
  const int* cols = rows + NE;
  const float* adj = (const float*)d_in[1];
  const float* embeds = (const float*)d_in[2];
  float* out = (float*)d_out;

  char* p = (char*)d_ws;
  auto alloc = [&](size_t bytes) {
    char* q = p;
    p += (bytes + 255) & ~(size_t)255;
    return q;
  };
  // zero region: cursor (doubles as level-0 counts) + 3 h-arrays + hist + cnt2
  size_t zero_bytes = (size_t)(4 * NBUK + HSIZE + 8) * 4;
  char* zero_base = (char*)alloc(zero_bytes);
  int* bucketCursor = (int*)zero_base;
  int* bucketCntS = bucketCursor + NBUK;   // h1,h2,h3
  int* hist = bucketCntS + 3 * NBUK;
  int* cnt2 = hist + HSIZE;  // [0]=collect count, [1]=cutoff bin

  int* bucketBaseS = (int*)alloc((size_t)4 * (NBUK + 1) * 4);
  int* rpAll = (int*)alloc((size_t)4 * (NN + 1) * 4);
  // padded pkBin (32 MB) dead after kB_emit; embA/embB overlay it
  size_t padBytes = (size_t)NBUK * BCAP * 16;
  char* unionAB = (char*)alloc(padBytes);
  int4* pkBin = (int4*)unionAB;
  float* embA = (float*)unionAB;                           // 12.8 MB
  float* embB = (float*)(unionAB + (size_t)NN * DD * 4);   // 12.8 MB
  int2* pk0 = (int2*)alloc((size_t)NE * 8);
  int2* pk1 = (int2*)alloc((size_t)CAP1 * 8);
  int2* pk2 = (int2*)alloc((size_t)CAP2 * 8);
  int2* pk3 = (int2*)alloc((size_t)CAP3 * 8);
  float* embS = (float*)alloc((size_t)NN * DD * 4);
  float* order0 = (float*)alloc(NN * 4);
  float* order1 = (float*)alloc(NN * 4);
  float* order2 = (float*)alloc(NN * 4);
  float* num1 = (float*)alloc(NN * 4);
  float* num2 = (float*)alloc(NN * 4);
  float* numS = (float*)alloc(NN * 4);
  unsigned long long* buf = (unsigned long long*)alloc(SORTN * 8);

  uint32_t dk[3][2];
  for (int i = 0; i < 3; ++i) tf2x32(0u, 42u, 0u, (uint32_t)i, dk[i][0], dk[i][1]);

  hipMemsetAsync(zero_base, 0, zero_bytes, stream);

  int gE = (NE + EPB - 1) / EPB;  // 391
  kA2_bin<<<gE, 1024, 0, stream>>>(rows, cols, adj, dk[0][0], dk[0][1], dk[1][0], dk[1][1],
                                   dk[2][0], dk[2][1], bucketCursor, pkBin, bucketCntS);
  k_scanBS<<<4, 512, 0, stream>>>(bucketCursor, bucketCntS, bucketBaseS);
  kB_emit<<<NBUK, 1024, 0, stream>>>(bucketBaseS, pkBin, rpAll,
                                     pk0, pk1, pk2, pk3, order0, order1, order2);

  const int* rp0 = rpAll;
  const int* rp1 = rpAll + (NN + 1);
  const int* rp2 = rpAll + 2 * (NN + 1);
  const int* rp3 = rpAll + 3 * (NN + 1);

  int gEmb = (NN * 32 + 255) / 256;
  k_emb0<<<gEmb, 256, 0, stream>>>(rp0, pk0, embeds, embA);

  // stage 1: emb cur=embA -> next=embB, num cur=order0 -> num1, sums init
  k_emb_step<<<gEmb, 256, 0, stream>>>(rp1, pk1, order0, embA, embB, embS,
                                       order0, num1, numS, 1);
  // stage 2: emb cur=embB -> next=embA, num cur=num1 -> num2, sums +=
  k_emb_step<<<gEmb, 256, 0, stream>>>(rp2, pk2, order1, embB, embA, embS,
                                       num1, num2, numS, 2);
  // stage 3: sums += only
  k_emb_step<<<gEmb, 256, 0, stream>>>(rp3, pk3, order2, embA, embB, embS,
                                       num2, num1, numS, 3);

  k_final<<<(NN + 255) / 256, 256, 0, stream>>>(embeds, embS, numS, 0u, 7u, out, hist);
  k_cutoff<<<1, 1024, 0, stream>>>(hist, cnt2 + 1);
  k_collect<<<(NN + 255) / 256, 256, 0, stream>>>(out, cnt2 + 1, buf, cnt2);
  k_rank<<<(SORTN + 255) / 256, 256, 0, stream>>>(buf, cnt2, out + NN);
}

// Round 9
// 334.005 us; speedup vs baseline: 1.0347x; 1.0347x over previous
//
#include <hip/hip_runtime.h>
#include <stdint.h>
#include <stddef.h>

#define NN 100000
#define NE 1600000
#define DD 32
#define NCAND 1024
#define HSIZE 65536
#define SORTN 4096
#define NBUK ((NN + 255) / 256)            // 391 buckets of 256 rows
#define EPB 4096                           // edges per block in kA2
#define BCAP 5120                          // padded bucket capacity (global pkBin)
#define BCAPL 4608                         // LDS working capacity (mean 4096 + 8 sd)
#define CHK 5                              // per-thread chunk in kB_emit (1024 thr)

// capacity for per-stage packed lists (mean + huge margin)
#define CAP1 832000
#define CAP2 432000
#define CAP3 240000

// ---------------- JAX threefry2x32 (20 rounds) ----------------
__host__ __device__ inline void tf2x32(uint32_t k0, uint32_t k1, uint32_t x0, uint32_t x1,
                                       uint32_t& o0, uint32_t& o1) {
  uint32_t ks2 = k0 ^ k1 ^ 0x1BD11BDAu;
  uint32_t v0 = x0 + k0, v1 = x1 + k1;
#define TFR(r) { v0 += v1; v1 = (v1 << (r)) | (v1 >> (32 - (r))); v1 ^= v0; }
  TFR(13) TFR(15) TFR(26) TFR(6)   v0 += k1;  v1 += ks2 + 1u;
  TFR(17) TFR(29) TFR(16) TFR(24)  v0 += ks2; v1 += k0 + 2u;
  TFR(13) TFR(15) TFR(26) TFR(6)   v0 += k0;  v1 += k1 + 3u;
  TFR(17) TFR(29) TFR(16) TFR(24)  v0 += k1;  v1 += ks2 + 4u;
  TFR(13) TFR(15) TFR(26) TFR(6)   v0 += ks2; v1 += k0 + 5u;
#undef TFR
  o0 = v0; o1 = v1;
}

__device__ __forceinline__ uint32_t jax_bits32(uint32_t k0, uint32_t k1, uint32_t i) {
  uint32_t o0, o1;
  tf2x32(k0, k1, 0u, i, o0, o1);
  return o0 ^ o1;
}

__device__ __forceinline__ float bits_to_uniform(uint32_t b) {
  return __fsub_rn(__uint_as_float((b >> 9) | 0x3f800000u), 1.0f);
}

// ---- numpy-pairwise sum of 32 floats held as 8 float4 REGISTERS ----
__device__ __forceinline__ float pw32c(float4 c0, float4 c1, float4 c2, float4 c3,
                                       float4 c4, float4 c5, float4 c6, float4 c7) {
  float r0 = __fadd_rn(__fadd_rn(__fadd_rn(c0.x, c2.x), c4.x), c6.x);
  float r1 = __fadd_rn(__fadd_rn(__fadd_rn(c0.y, c2.y), c4.y), c6.y);
  float r2 = __fadd_rn(__fadd_rn(__fadd_rn(c0.z, c2.z), c4.z), c6.z);
  float r3 = __fadd_rn(__fadd_rn(__fadd_rn(c0.w, c2.w), c4.w), c6.w);
  float r4 = __fadd_rn(__fadd_rn(__fadd_rn(c1.x, c3.x), c5.x), c7.x);
  float r5 = __fadd_rn(__fadd_rn(__fadd_rn(c1.y, c3.y), c5.y), c7.y);
  float r6 = __fadd_rn(__fadd_rn(__fadd_rn(c1.z, c3.z), c5.z), c7.z);
  float r7 = __fadd_rn(__fadd_rn(__fadd_rn(c1.w, c3.w), c5.w), c7.w);
  float a01 = __fadd_rn(r0, r1), a23 = __fadd_rn(r2, r3);
  float a45 = __fadd_rn(r4, r5), a67 = __fadd_rn(r6, r7);
  return __fadd_rn(__fadd_rn(a01, a23), __fadd_rn(a45, a67));
}

__device__ __forceinline__ float4 f4div1(float4 a, float d) {
  return make_float4(__fdiv_rn(a.x, d), __fdiv_rn(a.y, d),
                     __fdiv_rn(a.z, d), __fdiv_rn(a.w, d));
}
__device__ __forceinline__ float4 f4sq(float4 a) {
  return make_float4(__fmul_rn(a.x, a.x), __fmul_rn(a.y, a.y),
                     __fmul_rn(a.z, a.z), __fmul_rn(a.w, a.w));
}
__device__ __forceinline__ float4 f4dd(float4 s, float n1, float4 e, float n2) {
  return make_float4(__fmul_rn(__fdiv_rn(s.x, n1), __fdiv_rn(e.x, n2)),
                     __fmul_rn(__fdiv_rn(s.y, n1), __fdiv_rn(e.y, n2)),
                     __fmul_rn(__fdiv_rn(s.z, n1), __fdiv_rn(e.z, n2)),
                     __fmul_rn(__fdiv_rn(s.w, n1), __fdiv_rn(e.w, n2)));
}

// ---------------- preprocessing ----------------
__global__ __launch_bounds__(1024) void kA2_bin(
    const int* __restrict__ rows, const int* __restrict__ cols,
    const float* __restrict__ adj,
    uint32_t k00, uint32_t k01, uint32_t k10, uint32_t k11,
    uint32_t k20, uint32_t k21,
    int* __restrict__ bucketCursor, int4* __restrict__ pkBin,
    int* __restrict__ bucketCntS) {
  __shared__ int hist[NBUK];
  __shared__ int base[NBUK];
  __shared__ int h1[NBUK];
  __shared__ int h2[NBUK];
  __shared__ int h3[NBUK];
  __shared__ uint8_t lvs[EPB];
  __shared__ uint16_t rank16[EPB];
  int tid = threadIdx.x;
  for (int i = tid; i < NBUK; i += 1024) { hist[i] = 0; h1[i] = 0; h2[i] = 0; h3[i] = 0; }
  __syncthreads();
  int e0 = blockIdx.x * EPB;
#pragma unroll
  for (int k = 0; k < 4; ++k) {
    int e = e0 + k * 1024 + tid;
    int lv = 0;
    if (e < NE) {
      float u0 = bits_to_uniform(jax_bits32(k00, k01, (uint32_t)e));
      float u1 = bits_to_uniform(jax_bits32(k10, k11, (uint32_t)e));
      float u2 = bits_to_uniform(jax_bits32(k20, k21, (uint32_t)e));
      float kp0 = floorf(__fadd_rn(u0, 0.5f));
      float kp1 = floorf(__fadd_rn(u1, 0.25f));
      float kp2 = floorf(__fadd_rn(u2, 0.125f));
      if (kp0 != 0.0f) { lv = 1; if (kp1 != 0.0f) { lv = 2; if (kp2 != 0.0f) lv = 3; } }
      int b = rows[e] >> 8;
      rank16[k * 1024 + tid] = (uint16_t)atomicAdd(&hist[b], 1);
      if (lv >= 1) {
        atomicAdd(&h1[b], 1);
        if (lv >= 2) {
          atomicAdd(&h2[b], 1);
          if (lv >= 3) atomicAdd(&h3[b], 1);
        }
      }
    }
    lvs[k * 1024 + tid] = (uint8_t)lv;
  }
  __syncthreads();
  // bucketCursor's final value IS the level-0 total; no separate cnt0 atomic.
  for (int i = tid; i < NBUK; i += 1024) {
    int h = hist[i];
    base[i] = (h > 0) ? atomicAdd(&bucketCursor[i], h) : 0;
    if (h1[i]) atomicAdd(&bucketCntS[i], h1[i]);
    if (h2[i]) atomicAdd(&bucketCntS[NBUK + i], h2[i]);
    if (h3[i]) atomicAdd(&bucketCntS[2 * NBUK + i], h3[i]);
  }
  __syncthreads();
#pragma unroll
  for (int k = 0; k < 4; ++k) {
    int e = e0 + k * 1024 + tid;
    if (e < NE) {
      int r = rows[e];
      int b = r >> 8;
      int lv = (int)lvs[k * 1024 + tid];
      int pos = base[b] + (int)rank16[k * 1024 + tid];
      if (pos < BCAP)  // overflow guard (P~0)
        pkBin[(size_t)b * BCAP + pos] =
            make_int4(cols[e], __float_as_int(adj[e]), (e << 2) | lv, r);
    }
  }
}

// block a: a==0 scans bucketCursor (level-0 totals); a=1..3 scan h-arrays.
__global__ __launch_bounds__(512) void k_scanBS(const int* __restrict__ bucketCursor,
                                                const int* __restrict__ bucketCntS,
                                                int* __restrict__ bucketBaseS) {
  __shared__ int sb[512];
  int a = blockIdx.x;
  const int* c = (a == 0) ? bucketCursor : (bucketCntS + (size_t)(a - 1) * NBUK);
  int* o = bucketBaseS + (size_t)a * (NBUK + 1);
  int tid = threadIdx.x;
  int v = (tid < NBUK) ? c[tid] : 0;
  sb[tid] = v;
  __syncthreads();
  for (int off = 1; off < 512; off <<= 1) {
    int x = (tid >= off) ? sb[tid - off] : 0;
    __syncthreads();
    sb[tid] += x;
    __syncthreads();
  }
  if (tid < NBUK) o[tid] = sb[tid] - v;
  if (tid == NBUK - 1) o[NBUK] = sb[tid];
}

// per-bucket (1024 threads): load keys once, group, parallel rank-by-counting
// sort, order sums, coalesced emit.
__global__ __launch_bounds__(1024) void kB_emit(
    const int* __restrict__ bucketBaseS, const int4* __restrict__ pkBin,
    int* __restrict__ rpAll,
    int2* __restrict__ pk0, int2* __restrict__ pk1,
    int2* __restrict__ pk2, int2* __restrict__ pk3,
    float* __restrict__ order0, float* __restrict__ order1, float* __restrict__ order2) {
  __shared__ unsigned long long cnt64[256];
  __shared__ unsigned long long scan64[1024];  // 256-scan (phase 2) then emit scan
  __shared__ int start0[256];
  __shared__ int cur[256];
  __shared__ uint32_t keyF[BCAPL];   // original-index keys; reused as adjS after sort
  __shared__ uint32_t keyG[BCAPL];   // grouped keys, permuted to sorted in place
  __shared__ uint16_t origG[BCAPL];  // grouped slot -> original index (sorted in place)
  int b = blockIdx.x, tid = threadIdx.x;
  int bB0 = bucketBaseS[b];
  int n = bucketBaseS[b + 1] - bB0;
  if (n > BCAPL) n = BCAPL;  // LDS-safety clamp (P~0)
  size_t sRead = (size_t)b * BCAP;
  const int* pkI = (const int*)pkBin;          // int view: [col, adj, eidlv, row]
  const int2* pkZW = (const int2*)pkBin;       // int2 view: idx 2*i+1 = (eidlv, row)
  int r0 = b << 8;
  int nr = NN - r0; if (nr > 256) nr = 256;
  int bB1 = bucketBaseS[(NBUK + 1) + b];
  int bB2 = bucketBaseS[2 * (NBUK + 1) + b];
  int bB3 = bucketBaseS[3 * (NBUK + 1) + b];
  if (tid < 256) { cnt64[tid] = 0ull; cur[tid] = 0; }
  __syncthreads();
  // phase 1: load key halves, stash keyF, count per-row per-level
  for (int i = tid; i < n; i += 1024) {
    int2 zw = pkZW[2 * (sRead + (size_t)i) + 1];  // (eidlv, row)
    int lr = zw.y - r0;
    int lv = zw.x & 3;
    keyF[i] = ((uint32_t)lr << 23) | (uint32_t)zw.x;
    unsigned long long add = 1ull;
    if (lv >= 1) add |= 1ull << 16;
    if (lv >= 2) add |= 1ull << 32;
    if (lv >= 3) add |= 1ull << 48;
    atomicAdd(&cnt64[lr], add);
  }
  __syncthreads();
  // phase 2: 256-wide exclusive scan of packed counts
  unsigned long long own = (tid < 256) ? cnt64[tid] : 0ull;
  if (tid < 256) scan64[tid] = own;
  __syncthreads();
  for (int off = 1; off < 256; off <<= 1) {
    unsigned long long v = (tid < 256 && tid >= off) ? scan64[tid - off] : 0ull;
    __syncthreads();
    if (tid < 256) scan64[tid] += v;
    __syncthreads();
  }
  if (tid < 256) {
    unsigned long long ex = scan64[tid] - own;
    start0[tid] = (int)(ex & 0xFFFFull);
    if (tid < nr) {
      rpAll[r0 + tid] = bB0 + (int)(ex & 0xFFFFull);
      rpAll[(NN + 1) + r0 + tid] = bB1 + (int)((ex >> 16) & 0xFFFFull);
      rpAll[2 * (NN + 1) + r0 + tid] = bB2 + (int)((ex >> 32) & 0xFFFFull);
      rpAll[3 * (NN + 1) + r0 + tid] = bB3 + (int)((ex >> 48) & 0xFFFFull);
    }
  }
  if (b == NBUK - 1 && tid == 0) {
    rpAll[NN] = bucketBaseS[NBUK];
    rpAll[(NN + 1) + NN] = bucketBaseS[(NBUK + 1) + NBUK];
    rpAll[2 * (NN + 1) + NN] = bucketBaseS[2 * (NBUK + 1) + NBUK];
    rpAll[3 * (NN + 1) + NN] = bucketBaseS[3 * (NBUK + 1) + NBUK];
  }
  __syncthreads();
  // phase 3: group (LDS->LDS), scattering both index and key
  for (int i = tid; i < n; i += 1024) {
    uint32_t k = keyF[i];
    int lr = (int)(k >> 23);
    int slot = start0[lr] + atomicAdd(&cur[lr], 1);
    origG[slot] = (uint16_t)i;
    keyG[slot] = k;
  }
  __syncthreads();
  // phase 4: parallel rank-by-counting sort of each row segment
  int C2 = (n + 1023) >> 10;  // <= CHK
  {
    int lo2 = tid * C2, hi2 = lo2 + C2;
    if (lo2 > n) lo2 = n;
    if (hi2 > n) hi2 = n;
    uint16_t vals[CHK];
    uint16_t pos[CHK];
    uint32_t keys[CHK];
#pragma unroll
    for (int q = 0; q < CHK; ++q) {
      int i = lo2 + q;
      if (i < hi2) {
        uint32_t ki = keyG[i];
        int lr = (int)(ki >> 23);
        int st = start0[lr];
        int d = (int)(cnt64[lr] & 0xFFFFull);
        int rank = 0;
        for (int j = 0; j < d; ++j) rank += (keyG[st + j] < ki) ? 1 : 0;
        vals[q] = origG[i];
        keys[q] = ki;
        pos[q] = (uint16_t)(st + rank);
      }
    }
    __syncthreads();
#pragma unroll
    for (int q = 0; q < CHK; ++q) {
      int i = lo2 + q;
      if (i < hi2) { origG[pos[q]] = vals[q]; keyG[pos[q]] = keys[q]; }
    }
  }
  __syncthreads();
  // phase 5: stage adj bits (sorted order) into dead keyF
  uint32_t* adjS = keyF;
  {
    uint32_t av[CHK];
#pragma unroll
    for (int q = 0; q < CHK; ++q) {
      int i = tid + q * 1024;
      if (i < n) av[q] = (uint32_t)pkI[4 * (sRead + (size_t)origG[i]) + 1];
    }
#pragma unroll
    for (int q = 0; q < CHK; ++q) {
      int i = tid + q * 1024;
      if (i < n) adjS[i] = av[q];
    }
  }
  __syncthreads();
  // phase 6: orders in sorted (reference) order
  if (tid < nr) {
    int d = (int)(cnt64[tid] & 0xFFFFull);
    int st = start0[tid];
    float o0 = 0.0f, o1v = 0.0f, o2v = 0.0f;
    for (int i = 0; i < d; ++i) {
      int lv = (int)(keyG[st + i] & 3u);
      float a = __uint_as_float(adjS[st + i]);
      o0 = __fadd_rn(o0, a);
      if (lv >= 1) { o1v = __fadd_rn(o1v, a); if (lv >= 2) o2v = __fadd_rn(o2v, a); }
    }
    order0[r0 + tid] = o0; order1[r0 + tid] = o1v; order2[r0 + tid] = o2v;
  }
  // phase 7: chunked block scan of stage flags + coalesced emit
  int lo = tid * C2, hi = lo + C2;
  if (lo > n) lo = n;
  if (hi > n) hi = n;
  int c1 = 0, c2 = 0, c3 = 0;
  for (int i = lo; i < hi; ++i) {
    int lv = (int)(keyG[i] & 3u);
    c1 += (lv >= 1); c2 += (lv >= 2); c3 += (lv >= 3);
  }
  unsigned long long mine = (unsigned long long)c1 |
                            ((unsigned long long)c2 << 16) |
                            ((unsigned long long)c3 << 32);
  scan64[tid] = mine;
  __syncthreads();
  for (int off = 1; off < 1024; off <<= 1) {
    unsigned long long v = (tid >= off) ? scan64[tid - off] : 0ull;
    __syncthreads();
    scan64[tid] += v;
    __syncthreads();
  }
  unsigned long long ex = scan64[tid] - mine;
  int o1 = bB1 + (int)(ex & 0xFFFFull);
  int o2 = bB2 + (int)((ex >> 16) & 0xFFFFull);
  int o3 = bB3 + (int)((ex >> 32) & 0xFFFFull);
  {
    int colr[CHK];
#pragma unroll
    for (int q = 0; q < CHK; ++q) {
      int i = lo + q;
      if (i < hi) colr[q] = pkI[4 * (sRead + (size_t)origG[i])];
    }
#pragma unroll
    for (int q = 0; q < CHK; ++q) {
      int i = lo + q;
      if (i < hi) {
        int lv = (int)(keyG[i] & 3u);
        int2 pkv = make_int2(colr[q], (int)adjS[i]);
        pk0[bB0 + i] = pkv;  // sequential within bucket
        if (lv >= 1) {
          pk1[o1++] = pkv;
          if (lv >= 2) {
            pk2[o2++] = pkv;
            if (lv >= 3) pk3[o3++] = pkv;
          }
        }
      }
    }
  }
}

// ---------------- SpMM chain ----------------

// fst_emb = spmm(adj, embeds) - embeds
__global__ void k_emb0(const int* __restrict__ rp, const int2* __restrict__ pk,
                       const float* __restrict__ embeds, float* __restrict__ e0) {
  int tid = blockIdx.x * blockDim.x + threadIdx.x;
  int r = tid >> 5, d = tid & 31;
  if (r >= NN) return;
  int s = rp[r], t = rp[r + 1];
  float acc = 0.0f;
  for (int base = s; base < t; base += 32) {
    int idx = base + d;
    int2 p = (idx < t) ? pk[idx] : make_int2(0, 0);
    int m = t - base; if (m > 32) m = 32;
    for (int j = 0; j < m; j += 8) {
      int cc[8], aa[8];
      float xx[8];
#pragma unroll
      for (int q = 0; q < 8; ++q) {
        cc[q] = __shfl(p.x, j + q, 32);
        aa[q] = __shfl(p.y, j + q, 32);
      }
#pragma unroll
      for (int q = 0; q < 8; ++q) xx[q] = embeds[(size_t)cc[q] * DD + d];
#pragma unroll
      for (int q = 0; q < 8; ++q)
        acc = __fadd_rn(acc, __fmul_rn(__int_as_float(aa[q]), xx[q]));
    }
  }
  e0[(size_t)r * DD + d] = __fsub_rn(acc, embeds[(size_t)r * DD + d]);
}

// FUSED emb+num step (lane d==0 writes num outputs)
__global__ void k_emb_step(const int* __restrict__ rp, const int2* __restrict__ pk,
                           const float* __restrict__ ord, const float* __restrict__ ecur,
                           float* __restrict__ enext, float* __restrict__ esum,
                           const float* __restrict__ ncur, float* __restrict__ nnext,
                           float* __restrict__ nsum, int mode) {
  int tid = blockIdx.x * blockDim.x + threadIdx.x;
  int r = tid >> 5, d = tid & 31;
  if (r >= NN) return;
  int s = rp[r], t = rp[r + 1];
  float acc = 0.0f, accn = 0.0f;
  for (int base = s; base < t; base += 32) {
    int idx = base + d;
    int2 p = (idx < t) ? pk[idx] : make_int2(0, 0);
    int m = t - base; if (m > 32) m = 32;
    for (int j = 0; j < m; j += 8) {
      int cc[8], aa[8];
      float xx[8], nn[8];
#pragma unroll
      for (int q = 0; q < 8; ++q) {
        cc[q] = __shfl(p.x, j + q, 32);
        aa[q] = __shfl(p.y, j + q, 32);
      }
#pragma unroll
      for (int q = 0; q < 8; ++q) {
        xx[q] = ecur[(size_t)cc[q] * DD + d];
        nn[q] = ncur[cc[q]];
      }
#pragma unroll
      for (int q = 0; q < 8; ++q) {
        float av = __int_as_float(aa[q]);
        acc = __fadd_rn(acc, __fmul_rn(av, xx[q]));
        accn = __fadd_rn(accn, __fmul_rn(av, nn[q]));
      }
    }
  }
  float ordv = ord[r];
  size_t idx = (size_t)r * DD + d;
  float ec = ecur[idx];
  float o = __fsub_rn(__fsub_rn(acc, ec), __fmul_rn(ordv, ec));
  if (mode != 3) enext[idx] = o;
  if (mode == 1) esum[idx] = __fadd_rn(ec, o);
  else esum[idx] = __fadd_rn(esum[idx], o);
  if (d == 0) {
    float nc = ncur[r];
    float on = __fsub_rn(__fsub_rn(accn, nc), ordv);
    if (mode != 3) nnext[r] = on;
    if (mode == 1) nsum[r] = __fadd_rn(nc, on);
    else nsum[r] = __fadd_rn(nsum[r], on);
  }
}

// Scores — two-pass LDS-staged coalesced loads, single 33KB buffer.
// The monolithic k_final's float4 loads were 128B-strided (64 cache lines
// per wave-load) at 19% occupancy: exposed latency (6% VALUBusy, ~53-57us
// across 3 structural variants). Here thread t loads CONSECUTIVE float4s
// (16 transactions/wave); pass 1 stages emb_sum, computes s-regs + n1;
// pass 2 re-stages the same buffer with embeds, computes n2 + dot.
// All threads execute all barriers (loads clamped, store guarded).
// Math bit-identical to reference.
__global__ __launch_bounds__(256) void k_score(
    const float* __restrict__ embeds, const float* __restrict__ emb_sum,
    const float* __restrict__ num_sum, uint32_t gk0, uint32_t gk1,
    float* __restrict__ out_scores) {
  __shared__ float sm[256 * 33];
  int t = threadIdx.x;
  int b = blockIdx.x;
  int f4base = b * 2048;
  const float4* gS = (const float4*)emb_sum;
  const float4* gE = (const float4*)embeds;
  // pass 1: stage emb_sum (coalesced), compute s-registers + n1
#pragma unroll
  for (int k = 0; k < 8; ++k) {
    int loc = k * 256 + t;
    int g = f4base + loc;
    if (g < NN * 8) {
      int row = loc >> 3, c4 = loc & 7;
      float4 v = gS[g];
      float* d1 = &sm[row * 33 + c4 * 4];
      d1[0] = v.x; d1[1] = v.y; d1[2] = v.z; d1[3] = v.w;
    }
  }
  __syncthreads();
  int r = b * 256 + t;
  int rc = (r < NN) ? r : 0;  // clamp for loads; store is guarded
  float denom = __fadd_rn(num_sum[rc], 1e-8f);
  const float* rs = &sm[t * 33];
  float4 s0 = f4div1(make_float4(rs[0], rs[1], rs[2], rs[3]), denom);
  float4 s1 = f4div1(make_float4(rs[4], rs[5], rs[6], rs[7]), denom);
  float4 s2 = f4div1(make_float4(rs[8], rs[9], rs[10], rs[11]), denom);
  float4 s3 = f4div1(make_float4(rs[12], rs[13], rs[14], rs[15]), denom);
  float4 s4 = f4div1(make_float4(rs[16], rs[17], rs[18], rs[19]), denom);
  float4 s5 = f4div1(make_float4(rs[20], rs[21], rs[22], rs[23]), denom);
  float4 s6 = f4div1(make_float4(rs[24], rs[25], rs[26], rs[27]), denom);
  float4 s7 = f4div1(make_float4(rs[28], rs[29], rs[30], rs[31]), denom);
  float n1 = fmaxf(__fsqrt_rn(pw32c(f4sq(s0), f4sq(s1), f4sq(s2), f4sq(s3),
                                    f4sq(s4), f4sq(s5), f4sq(s6), f4sq(s7))), 1e-12f);
  __syncthreads();  // all sm reads done before overwrite
  // pass 2: stage embeds (coalesced), compute n2 + dot
#pragma unroll
  for (int k = 0; k < 8; ++k) {
    int loc = k * 256 + t;
    int g = f4base + loc;
    if (g < NN * 8) {
      int row = loc >> 3, c4 = loc & 7;
      float4 w = gE[g];
      float* d2 = &sm[row * 33 + c4 * 4];
      d2[0] = w.x; d2[1] = w.y; d2[2] = w.z; d2[3] = w.w;
    }
  }
  __syncthreads();
  float4 m0 = make_float4(rs[0], rs[1], rs[2], rs[3]);
  float4 m1 = make_float4(rs[4], rs[5], rs[6], rs[7]);
  float4 m2 = make_float4(rs[8], rs[9], rs[10], rs[11]);
  float4 m3 = make_float4(rs[12], rs[13], rs[14], rs[15]);
  float4 m4 = make_float4(rs[16], rs[17], rs[18], rs[19]);
  float4 m5 = make_float4(rs[20], rs[21], rs[22], rs[23]);
  float4 m6 = make_float4(rs[24], rs[25], rs[26], rs[27]);
  float4 m7 = make_float4(rs[28], rs[29], rs[30], rs[31]);
  float n2 = fmaxf(__fsqrt_rn(pw32c(f4sq(m0), f4sq(m1), f4sq(m2), f4sq(m3),
                                    f4sq(m4), f4sq(m5), f4sq(m6), f4sq(m7))), 1e-12f);
  float dot = pw32c(f4dd(s0, n1, m0, n2), f4dd(s1, n1, m1, n2),
                    f4dd(s2, n1, m2, n2), f4dd(s3, n1, m3, n2),
                    f4dd(s4, n1, m4, n2), f4dd(s5, n1, m5, n2),
                    f4dd(s6, n1, m6, n2), f4dd(s7, n1, m7, n2));
  float u = bits_to_uniform(jax_bits32(gk0, gk1, (uint32_t)rc));
  float l1 = (float)log((double)u);
  float w = -l1;
  float l2 = (float)log((double)w);
  float g = -l2;
  if (r < NN) out_scores[r] = __fadd_rn(dot, g);
}

// Histogram of score keys: 98 blocks x 1024, LDS open-addressing hash,
// <= 1 global atomic per distinct bin per block (chain <= 98). Cannot
// livelock: <= 1024 inserts into 1024 slots.
__global__ __launch_bounds__(1024) void k_hist(const float* __restrict__ scores,
                                               int* __restrict__ hist) {
  __shared__ uint32_t hb[1024];
  __shared__ uint32_t hc[1024];
  int t = threadIdx.x;
  int r = blockIdx.x * 1024 + t;
  hb[t] = 0xFFFFFFFFu;
  hc[t] = 0u;
  __syncthreads();
  if (r < NN) {
    uint32_t kb = __float_as_uint(scores[r]);
    kb = (kb & 0x80000000u) ? ~kb : (kb | 0x80000000u);
    uint32_t key = kb >> 16;
    uint32_t slot = (key * 2654435761u) >> 22;  // Fibonacci hash -> 10 bits
    for (;;) {
      uint32_t prev = atomicCAS(&hb[slot], 0xFFFFFFFFu, key);
      if (prev == 0xFFFFFFFFu || prev == key) { atomicAdd(&hc[slot], 1u); break; }
      slot = (slot + 1) & 1023u;
    }
  }
  __syncthreads();
  if (hb[t] != 0xFFFFFFFFu) atomicAdd(&hist[hb[t]], (int)hc[t]);
}

__global__ void k_cutoff(const int* __restrict__ hist, int* __restrict__ cutoff) {
  __shared__ int psum[1024];
  int t = threadIdx.x;
  int base = HSIZE - (t + 1) * 64;
  int own = 0;
  for (int i = 0; i < 64; ++i) own += hist[base + i];
  psum[t] = own;
  __syncthreads();
  for (int off = 1; off < 1024; off <<= 1) {
    int v = (t >= off) ? psum[t - off] : 0;
    __syncthreads();
    psum[t] += v;
    __syncthreads();
  }
  int incl = psum[t];
  int prev = incl - own;
  if (incl >= NCAND && prev < NCAND) {
    int c = prev;
    int b = HSIZE - t * 64 - 1;
    while (b >= base) {
      c += hist[b];
      if (c >= NCAND) break;
      --b;
    }
    *cutoff = b;
  }
}

__global__ void k_collect(const float* __restrict__ scores, const int* __restrict__ cutoff,
                          unsigned long long* __restrict__ buf, int* __restrict__ cnt2) {
  int r = blockIdx.x * blockDim.x + threadIdx.x;
  if (r >= NN) return;
  uint32_t kb = __float_as_uint(scores[r]);
  kb = (kb & 0x80000000u) ? ~kb : (kb | 0x80000000u);
  if ((int)(kb >> 16) >= *cutoff) {
    int p = atomicAdd(cnt2, 1);
    if (p < SORTN)
      buf[p] = ((unsigned long long)kb << 32) | (uint32_t)(~(uint32_t)r);
  }
}

// Rank-by-counting sort (keys unique -> ranks are a permutation).
__global__ __launch_bounds__(256) void k_rank(const unsigned long long* __restrict__ buf,
                                              const int* __restrict__ cnt2,
                                              float* __restrict__ out_cand) {
  __shared__ unsigned long long s[SORTN];
  int m = *cnt2;
  if (m > SORTN) m = SORTN;
  if (blockIdx.x * 256 >= m) return;  // whole block idle -> skip load
  for (int i = threadIdx.x; i < m; i += 256) s[i] = buf[i];
  __syncthreads();
  int i = blockIdx.x * 256 + threadIdx.x;
  if (i >= m) return;
  unsigned long long mine = s[i];
  int rank = 0;
  int j = 0;
  for (; j + 8 <= m; j += 8) {
#pragma unroll
    for (int q = 0; q < 8; ++q) rank += (s[j + q] > mine) ? 1 : 0;
  }
  for (; j < m; ++j) rank += (s[j] > mine) ? 1 : 0;
  if (rank < NCAND) {
    uint32_t idx = ~((uint32_t)(mine & 0xffffffffull));
    out_cand[rank] = (float)idx;
  }
}

// ---------------- host ----------------
extern "C" void kernel_launch(void* const* d_in, const int* in_sizes, int n_in,
                              void* d_out, int out_size, void* d_ws, size_t ws_size,
                              hipStream_t stream) {
  const int* rows = (const int*)d_in[0];
  const int* cols = rows + NE;
  const float* adj = (const float*)d_in[1];
  const float* embeds = (const float*)d_in[2];
  float* out = (float*)d_out;

  char* p = (char*)d_ws;
  auto alloc = [&](size_t bytes) {
    char* q = p;
    p += (bytes + 255) & ~(size_t)255;
    return q;
  };
  // zero region: cursor (doubles as level-0 counts) + 3 h-arrays + hist + cnt2
  size_t zero_bytes = (size_t)(4 * NBUK + HSIZE + 8) * 4;
  char* zero_base = (char*)alloc(zero_bytes);
  int* bucketCursor = (int*)zero_base;
  int* bucketCntS = bucketCursor + NBUK;   // h1,h2,h3
  int* hist = bucketCntS + 3 * NBUK;
  int* cnt2 = hist + HSIZE;  // [0]=collect count, [1]=cutoff bin

  int* bucketBaseS = (int*)alloc((size_t)4 * (NBUK + 1) * 4);
  int* rpAll = (int*)alloc((size_t)4 * (NN + 1) * 4);
  // padded pkBin (32 MB) dead after kB_emit; embA/embB overlay it
  size_t padBytes = (size_t)NBUK * BCAP * 16;
  char* unionAB = (char*)alloc(padBytes);
  int4* pkBin = (int4*)unionAB;
  float* embA = (float*)unionAB;                           // 12.8 MB
  float* embB = (float*)(unionAB + (size_t)NN * DD * 4);   // 12.8 MB
  int2* pk0 = (int2*)alloc((size_t)NE * 8);
  int2* pk1 = (int2*)alloc((size_t)CAP1 * 8);
  int2* pk2 = (int2*)alloc((size_t)CAP2 * 8);
  int2* pk3 = (int2*)alloc((size_t)CAP3 * 8);
  float* embS = (float*)alloc((size_t)NN * DD * 4);
  float* order0 = (float*)alloc(NN * 4);
  float* order1 = (float*)alloc(NN * 4);
  float* order2 = (float*)alloc(NN * 4);
  float* num1 = (float*)alloc(NN * 4);
  float* num2 = (float*)alloc(NN * 4);
  float* numS = (float*)alloc(NN * 4);
  unsigned long long* buf = (unsigned long long*)alloc(SORTN * 8);

  uint32_t dk[3][2];
  for (int i = 0; i < 3; ++i) tf2x32(0u, 42u, 0u, (uint32_t)i, dk[i][0], dk[i][1]);

  hipMemsetAsync(zero_base, 0, zero_bytes, stream);

  int gE = (NE + EPB - 1) / EPB;  // 391
  kA2_bin<<<gE, 1024, 0, stream>>>(rows, cols, adj, dk[0][0], dk[0][1], dk[1][0], dk[1][1],
                                   dk[2][0], dk[2][1], bucketCursor, pkBin, bucketCntS);
  k_scanBS<<<4, 512, 0, stream>>>(bucketCursor, bucketCntS, bucketBaseS);
  kB_emit<<<NBUK, 1024, 0, stream>>>(bucketBaseS, pkBin, rpAll,
                                     pk0, pk1, pk2, pk3, order0, order1, order2);

  const int* rp0 = rpAll;
  const int* rp1 = rpAll + (NN + 1);
  const int* rp2 = rpAll + 2 * (NN + 1);
  const int* rp3 = rpAll + 3 * (NN + 1);

  int gEmb = (NN * 32 + 255) / 256;
  k_emb0<<<gEmb, 256, 0, stream>>>(rp0, pk0, embeds, embA);

  // stage 1: emb cur=embA -> next=embB, num cur=order0 -> num1, sums init
  k_emb_step<<<gEmb, 256, 0, stream>>>(rp1, pk1, order0, embA, embB, embS,
                                       order0, num1, numS, 1);
  // stage 2: emb cur=embB -> next=embA, num cur=num1 -> num2, sums +=
  k_emb_step<<<gEmb, 256, 0, stream>>>(rp2, pk2, order1, embB, embA, embS,
                                       num1, num2, numS, 2);
  // stage 3: sums += only
  k_emb_step<<<gEmb, 256, 0, stream>>>(rp3, pk3, order2, embA, embB, embS,
                                       num2, num1, numS, 3);

  k_score<<<(NN + 255) / 256, 256, 0, stream>>>(embeds, embS, numS, 0u, 7u, out);
  k_hist<<<(NN + 1023) / 1024, 1024, 0, stream>>>(out, hist);
  k_cutoff<<<1, 1024, 0, stream>>>(hist, cnt2 + 1);
  k_collect<<<(NN + 255) / 256, 256, 0, stream>>>(out, cnt2 + 1, buf, cnt2);
  k_rank<<<(SORTN + 255) / 256, 256, 0, stream>>>(buf, cnt2, out + NN);
}